// Round 2
// baseline (1842.046 us; speedup 1.0000x reference)
//
#include <hip/hip_runtime.h>
#include <math.h>

#define B_ 4
#define C_ 256
#define RES_ 128
#define HW_ 16384
#define WF_ 65
#define F_ 8320

// ---- band id, bit-exact vs numpy float32 (no FMA contraction) ----
__device__ __forceinline__ int band_of(int row, int col){
  float yy = __fdiv_rn((float)row, 127.0f);
  float xx = __fdiv_rn((float)col, 64.0f);
  float rr = __fsqrt_rn(__fadd_rn(__fmul_rn(yy,yy), __fmul_rn(xx,xx)));
  float rm = __fadd_rn(__fsqrt_rn(2.0f), 1e-8f);
  float rn = __fdiv_rn(rr, rm);
  int b = (int)floorf(__fmul_rn(rn, 6.0f));
  return b > 5 ? 5 : b;
}

__device__ __forceinline__ float sigmoidf_(float v){ return 1.0f/(1.0f+expf(-v)); }

// ---- K0: (B,HW,C) -> (B,C,HW) transpose ----
__global__ __launch_bounds__(1024) void k_transpose(const float* __restrict__ x, float* __restrict__ x2){
  __shared__ float tile[64][65];
  int b = blockIdx.z;
  int hw0 = blockIdx.x*64, c0 = blockIdx.y*64;
  int tx = threadIdx.x, ty = threadIdx.y;
  #pragma unroll
  for (int i=0;i<4;i++){
    int hw = hw0 + ty + i*16;
    tile[ty+i*16][tx] = x[((size_t)b*HW_ + hw)*C_ + c0 + tx];
  }
  __syncthreads();
  #pragma unroll
  for (int i=0;i<4;i++){
    int c = c0 + ty + i*16;
    x2[((size_t)b*C_ + c)*HW_ + hw0 + tx] = tile[tx][ty+i*16];
  }
}

// ---- K1: row rFFT (length 128 -> 65 bins), no scale. x2 -> X1 ----
__global__ __launch_bounds__(256) void k_rowfft(const float* __restrict__ x2, float2* __restrict__ X1){
  int g = blockIdx.x*256 + threadIdx.x;          // exactly B*C*128*65 threads
  int kx = g % WF_;
  int t  = g / WF_;
  int y  = t % RES_;
  int bc = t / RES_;
  const float* row = x2 + (size_t)bc*HW_ + y*RES_;
  float sr, cr;
  sincosf(-6.283185307179586f * (float)kx / 128.0f, &sr, &cr);
  float wr = 1.0f, wi = 0.0f, ar = 0.0f, ai = 0.0f;
  #pragma unroll 8
  for (int n=0; n<RES_; n++){
    float v = row[n];
    ar += v*wr; ai += v*wi;
    float nw = wr*cr - wi*sr;
    wi = wr*sr + wi*cr; wr = nw;
  }
  X1[g] = make_float2(ar, ai);
}

// ---- K2: column FFT over y (e^{-i}), ortho scale 1/128. X1 -> Xf ----
__global__ __launch_bounds__(256) void k_colfft(const float2* __restrict__ X1, float2* __restrict__ Xf){
  __shared__ float2 tw[RES_];
  int tid = threadIdx.x;
  if (tid < RES_){
    float s, c; sincosf(6.283185307179586f * (float)tid / 128.0f, &s, &c);
    tw[tid] = make_float2(c, s);
  }
  __syncthreads();
  int g   = blockIdx.x*256 + tid;                // B*C*16*65 threads
  int kx  = g % WF_;
  int q   = g / WF_;
  int kyg = q & 15;
  int bc  = q >> 4;
  const float2* col = X1 + (size_t)bc*F_ + kx;
  float ar[8]={0,0,0,0,0,0,0,0}, ai[8]={0,0,0,0,0,0,0,0};
  int jj[8]={0,0,0,0,0,0,0,0};
  int kys[8];
  #pragma unroll
  for (int i=0;i<8;i++) kys[i] = kyg*8 + i;
  for (int y=0; y<RES_; y++){
    float2 v = col[y*WF_];
    #pragma unroll
    for (int i=0;i<8;i++){
      float2 w = tw[jj[i]];                      // e^{-i th} = (c, -s)
      ar[i] += v.x*w.x + v.y*w.y;
      ai[i] += v.y*w.x - v.x*w.y;
      jj[i] = (jj[i] + kys[i]) & 127;
    }
  }
  #pragma unroll
  for (int i=0;i<8;i++)
    Xf[((size_t)bc*RES_ + kys[i])*WF_ + kx] = make_float2(ar[i]*0.0078125f, ai[i]*0.0078125f);
}

// ---- pointwise channel linear: xcs[b,c,hw] = sum_d x[b,hw,d] lin_w[c,d] + lin_b[c] ----
__global__ __launch_bounds__(256) void k_pointwise(const float* __restrict__ x2, const float* __restrict__ lw,
                                                   const float* __restrict__ lb, float* __restrict__ xcs){
  __shared__ float wsh[32][256];
  int tid = threadIdx.x;
  int b = blockIdx.z, c0 = blockIdx.y*32, hw = blockIdx.x*256 + tid;
  #pragma unroll
  for (int i=0;i<32;i++) wsh[i][tid] = lw[(c0+i)*C_ + tid];
  __syncthreads();
  float acc[32];
  #pragma unroll
  for (int i=0;i<32;i++) acc[i] = 0.0f;
  for (int d=0; d<C_; d++){
    float v = x2[((size_t)(b*C_ + d))*HW_ + hw];
    #pragma unroll
    for (int i=0;i<32;i++) acc[i] += wsh[i][d]*v;
  }
  #pragma unroll
  for (int i=0;i<32;i++)
    xcs[((size_t)(b*C_ + c0 + i))*HW_ + hw] = acc[i] + lb[c0+i];
}

// ---- depthwise 3x3 conv (SAME, zero pad), accumulate into xcs ----
__global__ __launch_bounds__(256) void k_conv(const float* __restrict__ x2, const float* __restrict__ cw,
                                              float* __restrict__ xcs){
  int g = blockIdx.x*256 + threadIdx.x;
  int xx = g & 127, yy = (g>>7)&127, bc = g>>14, c = bc & 255;
  const float* img = x2 + (size_t)bc*HW_;
  const float* w9 = cw + c*9;
  float a = xcs[g];
  #pragma unroll
  for (int dy=-1; dy<=1; dy++){
    int y2 = yy+dy; if ((unsigned)y2 >= 128u) continue;
    #pragma unroll
    for (int dx=-1; dx<=1; dx++){
      int x3 = xx+dx; if ((unsigned)x3 >= 128u) continue;
      a += img[y2*128 + x3] * w9[(dy+1)*3 + (dx+1)];
    }
  }
  xcs[g] = a;
}

// ---- band |Xf| sums per (b,c) ----
__global__ __launch_bounds__(256) void k_bandsum(const float2* __restrict__ Xf, float* __restrict__ bsums){
  int bc = blockIdx.x, tid = threadIdx.x;
  const float2* p = Xf + (size_t)bc*F_;
  float acc[6] = {0,0,0,0,0,0};
  for (int f = tid; f < F_; f += 256){
    int row = f / WF_, col = f - row*WF_;
    float2 v = p[f];
    float m = __fsqrt_rn(v.x*v.x + v.y*v.y);
    int bnd = band_of(row, col);
    #pragma unroll
    for (int n=0;n<6;n++) acc[n] += (bnd==n) ? m : 0.0f;
  }
  __shared__ float red[6][256];
  #pragma unroll
  for (int n=0;n<6;n++) red[n][tid] = acc[n];
  __syncthreads();
  for (int s=128; s>0; s>>=1){
    if (tid < s){
      #pragma unroll
      for (int n=0;n<6;n++) red[n][tid] += red[n][tid+s];
    }
    __syncthreads();
  }
  if (tid < 6) bsums[bc*6 + tid] = red[tid][0];
}

// ---- band counts (static) ----
__global__ __launch_bounds__(256) void k_counts(float* __restrict__ counts){
  int tid = threadIdx.x;
  float acc[6] = {0,0,0,0,0,0};
  for (int f = tid; f < F_; f += 256){
    int row = f / WF_, col = f - row*WF_;
    int bnd = band_of(row, col);
    #pragma unroll
    for (int n=0;n<6;n++) acc[n] += (bnd==n) ? 1.0f : 0.0f;
  }
  __shared__ float red[6][256];
  #pragma unroll
  for (int n=0;n<6;n++) red[n][tid] = acc[n];
  __syncthreads();
  for (int s=128; s>0; s>>=1){
    if (tid < s){
      #pragma unroll
      for (int n=0;n<6;n++) red[n][tid] += red[n][tid+s];
    }
    __syncthreads();
  }
  if (tid < 6) counts[tid] = fmaxf(red[tid][0], 1.0f);
}

// ---- gate MLP: means -> relu(128) -> sigmoid(6) per (b,c) ----
__global__ __launch_bounds__(256) void k_mlp(const float* __restrict__ bsums, const float* __restrict__ counts,
                                             const float* __restrict__ w1, const float* __restrict__ b1,
                                             const float* __restrict__ w2, const float* __restrict__ b2,
                                             float* __restrict__ alpha){
  int t = blockIdx.x*256 + threadIdx.x;
  if (t >= B_*C_) return;
  float means[6];
  #pragma unroll
  for (int n=0;n<6;n++) means[n] = bsums[t*6+n] / (counts[n] + 1e-6f);
  float acc[6] = {0,0,0,0,0,0};
  for (int j=0;j<128;j++){
    float h = b1[j];
    #pragma unroll
    for (int n=0;n<6;n++) h += means[n]*w1[j*6+n];
    h = fmaxf(h, 0.0f);
    #pragma unroll
    for (int n=0;n<6;n++) acc[n] += h*w2[n*128+j];
  }
  #pragma unroll
  for (int n=0;n<6;n++) alpha[t*6+n] = sigmoidf_(acc[n] + b2[n]);
}

// ---- complex channel mix inside low-freq mask: mapped = W @ Xf_low ----
__global__ __launch_bounds__(256) void k_mix(const float2* __restrict__ Xf, const float* __restrict__ wre,
                                             const float* __restrict__ wim, const float* __restrict__ kxp,
                                             const float* __restrict__ kyp, float2* __restrict__ mapped){
  int f = blockIdx.x*256 + threadIdx.x;
  if (f >= F_) return;
  int row = f / WF_, col = f - row*WF_;
  float rowlim = floorf(sigmoidf_(kxp[0])*128.0f);
  float collim = floorf(sigmoidf_(kyp[0])*65.0f);
  if (!((float)row < rowlim && (float)col < collim)) return;
  int b = blockIdx.z, c0 = blockIdx.y*4;
  float ar[4]={0,0,0,0}, ai[4]={0,0,0,0};
  const float2* xb = Xf + (size_t)b*C_*F_ + f;
  for (int d=0; d<C_; d++){
    float2 v = xb[(size_t)d*F_];
    #pragma unroll
    for (int i=0;i<4;i++){
      float wr = wre[(c0+i)*C_ + d];
      float wi = wim[(c0+i)*C_ + d];
      ar[i] += wr*v.x - wi*v.y;
      ai[i] += wr*v.y + wi*v.x;
    }
  }
  #pragma unroll
  for (int i=0;i<4;i++)
    mapped[((size_t)(b*C_ + c0 + i))*F_ + f] = make_float2(ar[i], ai[i]);
}

// ---- fuse: Z = inmask ? a*mapped : (1-a)*Xf  (in-place into Xf) ----
__global__ __launch_bounds__(256) void k_fuse(float2* __restrict__ Xf, const float2* __restrict__ mapped,
                                              const float* __restrict__ alpha, const float* __restrict__ kxp,
                                              const float* __restrict__ kyp){
  int g = blockIdx.x*256 + threadIdx.x;          // B*C*F threads
  int bc = g / F_, f = g - bc*F_;
  int row = f / WF_, col = f - row*WF_;
  float rowlim = floorf(sigmoidf_(kxp[0])*128.0f);
  float collim = floorf(sigmoidf_(kyp[0])*65.0f);
  bool inmask = ((float)row < rowlim) && ((float)col < collim);
  float a = alpha[bc*6 + band_of(row, col)];
  float2 z;
  if (inmask){
    float2 m = mapped[g];
    z = make_float2(a*m.x, a*m.y);
  } else {
    float2 v = Xf[g];
    float om = 1.0f - a;
    z = make_float2(om*v.x, om*v.y);
  }
  Xf[g] = z;
}

// ---- inverse column FFT over ky (e^{+i}), no scale. Z -> Y1 ----
__global__ __launch_bounds__(256) void k_invcol(const float2* __restrict__ Z, float2* __restrict__ Y1){
  __shared__ float2 tw[RES_];
  int tid = threadIdx.x;
  if (tid < RES_){
    float s, c; sincosf(6.283185307179586f * (float)tid / 128.0f, &s, &c);
    tw[tid] = make_float2(c, s);
  }
  __syncthreads();
  int g   = blockIdx.x*256 + tid;
  int kx  = g % WF_;
  int q   = g / WF_;
  int yg  = q & 15;
  int bc  = q >> 4;
  const float2* col = Z + (size_t)bc*F_ + kx;
  float ar[8]={0,0,0,0,0,0,0,0}, ai[8]={0,0,0,0,0,0,0,0};
  int jj[8]={0,0,0,0,0,0,0,0};
  int ys[8];
  #pragma unroll
  for (int i=0;i<8;i++) ys[i] = yg*8 + i;
  for (int ky=0; ky<RES_; ky++){
    float2 v = col[ky*WF_];
    #pragma unroll
    for (int i=0;i<8;i++){
      float2 w = tw[jj[i]];                      // e^{+i th} = (c, s)
      ar[i] += v.x*w.x - v.y*w.y;
      ai[i] += v.x*w.y + v.y*w.x;
      jj[i] = (jj[i] + ys[i]) & 127;
    }
  }
  #pragma unroll
  for (int i=0;i<8;i++)
    Y1[((size_t)bc*RES_ + ys[i])*WF_ + kx] = make_float2(ar[i], ai[i]);
}

// ---- inverse row half-complex FFT (drops Im at kx=0,64), scale 1/128, + (xl+xc) -> s ----
__global__ __launch_bounds__(256) void k_invrow(const float2* __restrict__ Y1, const float* __restrict__ xcs,
                                                float* __restrict__ sbuf){
  int g = blockIdx.x*256 + threadIdx.x;
  int x = g & 127, y = (g>>7)&127, bc = g>>14;
  const float2* row = Y1 + ((size_t)bc*RES_ + y)*WF_;
  float sr, cr;
  sincosf(6.283185307179586f * (float)x / 128.0f, &sr, &cr);
  float wr = 1.0f, wi = 0.0f, acc = 0.0f;
  #pragma unroll 13
  for (int k=0; k<WF_; k++){
    float2 v = row[k];
    float wgt = (k==0 || k==64) ? 1.0f : 2.0f;
    acc += wgt*(v.x*wr - v.y*wi);
    float nw = wr*cr - wi*sr;
    wi = wr*sr + wi*cr; wr = nw;
  }
  sbuf[g] = acc * 0.0078125f + xcs[g];
}

// ---- LN stats over channels ----
__global__ __launch_bounds__(256) void k_stats(const float* __restrict__ sbuf, float* __restrict__ stats){
  int g = blockIdx.x*256 + threadIdx.x;          // B*HW threads
  int b = g >> 14, hw = g & 16383;
  const float* p = sbuf + (size_t)b*C_*HW_ + hw;
  float s1 = 0.0f, s2 = 0.0f;
  for (int c=0; c<C_; c++){
    float v = p[(size_t)c*HW_];
    s1 += v; s2 += v*v;
  }
  float mean = s1 * (1.0f/256.0f);
  float var  = s2 * (1.0f/256.0f) - mean*mean;
  stats[g] = mean;
  stats[65536 + g] = 1.0f / sqrtf(var + 1e-5f);
}

// ---- LN apply + conditional scale/shift, transpose to (B,HW,C) ----
__global__ __launch_bounds__(256) void k_apply(const float* __restrict__ sbuf, const float* __restrict__ stats,
                                               const float* __restrict__ timev,
                                               const float* __restrict__ nww, const float* __restrict__ nwb,
                                               const float* __restrict__ nbw, const float* __restrict__ nbb,
                                               float* __restrict__ out){
  int g = blockIdx.x*256 + threadIdx.x;          // B*HW*C, c fastest
  int c = g & 255;
  int hw = (g >> 8) & 16383;
  int b = g >> 22;
  float v = sbuf[((size_t)(b*C_ + c))*HW_ + hw];
  float mean = stats[(b<<14) + hw];
  float rstd = stats[65536 + (b<<14) + hw];
  float t = timev[b];
  float w = t*nww[c] + nwb[c];
  float bi = t*nbw[c] + nbb[c];
  out[g] = w * ((v - mean) * rstd) + bi;
}

extern "C" void kernel_launch(void* const* d_in, const int* in_sizes, int n_in,
                              void* d_out, int out_size, void* d_ws, size_t ws_size,
                              hipStream_t stream){
  const float* x      = (const float*)d_in[0];
  const float* timev  = (const float*)d_in[1];
  const float* w_real = (const float*)d_in[2];
  const float* w_imag = (const float*)d_in[3];
  const float* conv_w = (const float*)d_in[4];
  const float* lin_w  = (const float*)d_in[5];
  const float* lin_b  = (const float*)d_in[6];
  const float* mlp_w1 = (const float*)d_in[7];
  const float* mlp_b1 = (const float*)d_in[8];
  const float* mlp_w2 = (const float*)d_in[9];
  const float* mlp_b2 = (const float*)d_in[10];
  const float* norm_ww= (const float*)d_in[11];
  const float* norm_wb= (const float*)d_in[12];
  const float* norm_bw= (const float*)d_in[13];
  const float* norm_bb= (const float*)d_in[14];
  const float* kxp    = (const float*)d_in[15];
  const float* kyp    = (const float*)d_in[16];

  // workspace layout (floats) — total 50,999,360 floats = 194.6 MiB
  float* ws = (float*)d_ws;
  float*  alpha = ws;                               // 6144
  float*  bsums = ws + 6144;                        // 6144
  float*  counts= ws + 12288;                       // 8 (padded to 64)
  float*  stats = ws + 12352;                       // 131072 (mean | rstd)
  float*  x2    = ws + 143424;                      // 16,777,216   (x2, later final sum s)
  float2* Xf    = (float2*)(ws + 16920640);         // 8,519,680 f2 (Xf, then fused Z in-place)
  float2* Cb    = (float2*)(ws + 33960000);         // 8,519,680 f2 (X1 -> mapped -> Y1)
  float*  xcs   = (float*)d_out;                    // xc + xl, scratch in d_out (dead before k_apply)
  float*  out   = (float*)d_out;

  k_transpose<<<dim3(256, 4, B_), dim3(64,16), 0, stream>>>(x, x2);
  k_rowfft  <<<33280, 256, 0, stream>>>(x2, Cb);
  k_colfft  <<<4160, 256, 0, stream>>>(Cb, Xf);
  k_pointwise<<<dim3(64, 8, B_), 256, 0, stream>>>(x2, lin_w, lin_b, xcs);
  k_conv    <<<65536, 256, 0, stream>>>(x2, conv_w, xcs);
  k_bandsum <<<1024, 256, 0, stream>>>(Xf, bsums);
  k_counts  <<<1, 256, 0, stream>>>(counts);
  k_mlp     <<<4, 256, 0, stream>>>(bsums, counts, mlp_w1, mlp_b1, mlp_w2, mlp_b2, alpha);
  k_mix     <<<dim3(33, 64, B_), 256, 0, stream>>>(Xf, w_real, w_imag, kxp, kyp, Cb);
  k_fuse    <<<33280, 256, 0, stream>>>(Xf, Cb, alpha, kxp, kyp);
  k_invcol  <<<4160, 256, 0, stream>>>(Xf, Cb);
  k_invrow  <<<65536, 256, 0, stream>>>(Cb, xcs, x2);
  k_stats   <<<256, 256, 0, stream>>>(x2, stats);
  k_apply   <<<65536, 256, 0, stream>>>(x2, stats, timev, norm_ww, norm_wb, norm_bw, norm_bb, out);
}

// Round 3
// 929.182 us; speedup vs baseline: 1.9824x; 1.9824x over previous
//
#include <hip/hip_runtime.h>
#include <math.h>

#define B_ 4
#define C_ 256
#define RES_ 128
#define HW_ 16384
#define WF_ 65
#define F_ 8320

__device__ __forceinline__ int brev7(int j){ return (int)(__brev((unsigned)j) >> 25); }

// ---- band id, bit-exact vs numpy float32 (no FMA contraction) ----
__device__ __forceinline__ int band_of(int row, int col){
  float yy = __fdiv_rn((float)row, 127.0f);
  float xx = __fdiv_rn((float)col, 64.0f);
  float rr = __fsqrt_rn(__fadd_rn(__fmul_rn(yy,yy), __fmul_rn(xx,xx)));
  float rm = __fadd_rn(__fsqrt_rn(2.0f), 1e-8f);
  float rn = __fdiv_rn(rr, rm);
  int b = (int)floorf(__fmul_rn(rn, 6.0f));
  return b > 5 ? 5 : b;
}

__device__ __forceinline__ float sigmoidf_(float v){ return 1.0f/(1.0f+expf(-v)); }

// ---- in-LDS radix-2 DIF FFT, length 128, batched over nrows rows of stride rstride.
// Natural-order input; output at position j holds X[brev7(j)]. SGN=-1 fwd, +1 inv.
template<int SGN, int NROWS>
__device__ __forceinline__ void fft128_lds(float2* buf, int rstride, int tid, const float2* tw){
  const int total = NROWS*64;
  #pragma unroll
  for (int stage=0; stage<7; stage++){
    int half = 64 >> stage;
    __syncthreads();
    for (int idx = tid; idx < total; idx += 256){
      int row = idx % NROWS;
      int t   = idx / NROWS;
      int j   = t & (half-1);
      int i0  = ((t >> (6-stage)) << (7-stage)) + j;
      int i1  = i0 + half;
      float2* rb = buf + row*rstride;
      float2 a = rb[i0], b = rb[i1];
      float2 w = tw[j << stage];
      float dx = a.x - b.x, dy = a.y - b.y;
      rb[i0] = make_float2(a.x+b.x, a.y+b.y);
      float ws = (SGN < 0) ? -w.y : w.y;
      rb[i1] = make_float2(dx*w.x - dy*ws, dx*ws + dy*w.x);
    }
  }
  __syncthreads();
}

// ---- K0: (B,HW,C) -> (B,C,HW) transpose ----
__global__ __launch_bounds__(1024) void k_transpose(const float* __restrict__ x, float* __restrict__ x2){
  __shared__ float tile[64][65];
  int b = blockIdx.z;
  int hw0 = blockIdx.x*64, c0 = blockIdx.y*64;
  int tx = threadIdx.x, ty = threadIdx.y;
  #pragma unroll
  for (int i=0;i<4;i++){
    int hw = hw0 + ty + i*16;
    tile[ty+i*16][tx] = x[((size_t)b*HW_ + hw)*C_ + c0 + tx];
  }
  __syncthreads();
  #pragma unroll
  for (int i=0;i<4;i++){
    int c = c0 + ty + i*16;
    x2[((size_t)b*C_ + c)*HW_ + hw0 + tx] = tile[tx][ty+i*16];
  }
}

// ---- counts + band-id table (single block) ----
__global__ __launch_bounds__(256) void k_counts(float* __restrict__ counts, unsigned char* __restrict__ bid){
  int tid = threadIdx.x;
  float acc[6] = {0,0,0,0,0,0};
  for (int f = tid; f < F_; f += 256){
    int row = f / WF_, col = f - row*WF_;
    int bnd = band_of(row, col);
    bid[f] = (unsigned char)bnd;
    #pragma unroll
    for (int n=0;n<6;n++) acc[n] += (bnd==n) ? 1.0f : 0.0f;
  }
  __shared__ float red[6][256];
  #pragma unroll
  for (int n=0;n<6;n++) red[n][tid] = acc[n];
  __syncthreads();
  for (int s=128; s>0; s>>=1){
    if (tid < s){
      #pragma unroll
      for (int n=0;n<6;n++) red[n][tid] += red[n][tid+s];
    }
    __syncthreads();
  }
  if (tid < 6) counts[tid] = fmaxf(red[tid][0], 1.0f);
}

// ---- forward row rFFT (radix-2): x2 -> X1 (bins 0..64, no scale) ----
__global__ __launch_bounds__(256) void k_fwd_rows(const float* __restrict__ x2, float2* __restrict__ X1){
  __shared__ float2 buf[32*129];
  __shared__ float2 tw[64];
  int tid = threadIdx.x;
  if (tid < 64){ float s,c; sincosf(6.283185307179586f*(float)tid/128.0f,&s,&c); tw[tid]=make_float2(c,s); }
  int slice = blockIdx.x >> 2;
  int r0 = (blockIdx.x & 3) * 32;
  const float4* src = (const float4*)(x2 + (size_t)slice*HW_ + (size_t)r0*128);
  #pragma unroll
  for (int q=0; q<4; q++){
    int f4 = tid + 256*q;                 // 0..1023
    float4 v = src[f4];
    int pos = f4*4;
    int row = pos >> 7, i = pos & 127;
    float2* rb = buf + row*129 + i;
    rb[0] = make_float2(v.x, 0.0f);
    rb[1] = make_float2(v.y, 0.0f);
    rb[2] = make_float2(v.z, 0.0f);
    rb[3] = make_float2(v.w, 0.0f);
  }
  fft128_lds<-1,32>(buf, 129, tid, tw);
  float2* dst = X1 + (size_t)slice*F_ + (size_t)r0*WF_;
  for (int p = tid; p < 32*WF_; p += 256){
    int row = p / WF_, k = p - row*WF_;
    dst[p] = buf[row*129 + brev7(k)];
  }
}

// ---- forward col FFT + ortho scale + band-gate (bandsum + MLP -> alpha) ----
__global__ __launch_bounds__(256) void k_fwd_cols_gate(const float2* __restrict__ X1, float2* __restrict__ Xf,
                                                       const float* __restrict__ counts, const unsigned char* __restrict__ bid,
                                                       const float* __restrict__ w1, const float* __restrict__ b1,
                                                       const float* __restrict__ w2, const float* __restrict__ b2,
                                                       float* __restrict__ alpha){
  __shared__ float2 cbuf[13*129];
  __shared__ float2 tw[64];
  __shared__ float red[6][256];
  __shared__ float means[6], h[128];
  int tid = threadIdx.x;
  if (tid < 64){ float s,c; sincosf(6.283185307179586f*(float)tid/128.0f,&s,&c); tw[tid]=make_float2(c,s); }
  int slice = blockIdx.x;
  const float2* xin = X1 + (size_t)slice*F_;
  float2* xout = Xf + (size_t)slice*F_;
  float acc[6] = {0,0,0,0,0,0};
  for (int chunk=0; chunk<5; chunk++){
    int c0 = chunk*13;
    __syncthreads();
    for (int p = tid; p < 13*128; p += 256){
      int y = p / 13, col = p - y*13;
      cbuf[col*129 + y] = xin[y*WF_ + c0 + col];
    }
    fft128_lds<-1,13>(cbuf, 129, tid, tw);
    for (int p = tid; p < 13*128; p += 256){
      int ky = p / 13, col = p - ky*13, kx = c0 + col;
      float2 v = cbuf[col*129 + brev7(ky)];
      v.x *= 0.0078125f; v.y *= 0.0078125f;
      int f = ky*WF_ + kx;
      xout[f] = v;
      float m = __fsqrt_rn(v.x*v.x + v.y*v.y);
      int bb = (int)bid[f];
      #pragma unroll
      for (int n=0;n<6;n++) acc[n] += (bb==n) ? m : 0.0f;
    }
  }
  __syncthreads();
  #pragma unroll
  for (int n=0;n<6;n++) red[n][tid] = acc[n];
  __syncthreads();
  for (int s=128; s>0; s>>=1){
    if (tid < s){
      #pragma unroll
      for (int n=0;n<6;n++) red[n][tid] += red[n][tid+s];
    }
    __syncthreads();
  }
  if (tid < 6) means[tid] = red[tid][0] / (counts[tid] + 1e-6f);
  __syncthreads();
  if (tid < 128){
    float hv = b1[tid];
    #pragma unroll
    for (int n=0;n<6;n++) hv += means[n]*w1[tid*6+n];
    h[tid] = fmaxf(hv, 0.0f);
  }
  __syncthreads();
  if (tid < 6){
    float o = b2[tid];
    for (int j=0;j<128;j++) o += h[j]*w2[tid*128+j];
    alpha[slice*6 + tid] = sigmoidf_(o);
  }
}

// ---- pointwise channel linear: xcs[b,c,hw] = sum_d x2[b,d,hw] lin_w[c,d] + lin_b[c] ----
__global__ __launch_bounds__(256) void k_pointwise(const float* __restrict__ x2, const float* __restrict__ lw,
                                                   const float* __restrict__ lb, float* __restrict__ xcs){
  __shared__ float4 wsh[256][8];           // [d][i/4] — reads are wave-uniform broadcasts
  int tid = threadIdx.x;
  int b = blockIdx.z, c0 = blockIdx.y*32, hw = blockIdx.x*256 + tid;
  float* wr = (float*)&wsh[tid][0];
  #pragma unroll
  for (int i=0;i<32;i++) wr[i] = lw[(c0+i)*C_ + tid];
  __syncthreads();
  float acc[32];
  #pragma unroll
  for (int i=0;i<32;i++) acc[i] = 0.0f;
  for (int d=0; d<C_; d++){
    float v = x2[((size_t)(b*C_ + d))*HW_ + hw];
    float4* wp = &wsh[d][0];
    #pragma unroll
    for (int i8=0;i8<8;i8++){
      float4 w4 = wp[i8];
      acc[4*i8+0] += w4.x*v; acc[4*i8+1] += w4.y*v;
      acc[4*i8+2] += w4.z*v; acc[4*i8+3] += w4.w*v;
    }
  }
  #pragma unroll
  for (int i=0;i<32;i++)
    xcs[((size_t)(b*C_ + c0 + i))*HW_ + hw] = acc[i] + lb[c0+i];
}

// ---- depthwise 3x3 conv (SAME, zero pad), accumulate into xcs ----
__global__ __launch_bounds__(256) void k_conv(const float* __restrict__ x2, const float* __restrict__ cw,
                                              float* __restrict__ xcs){
  int g = blockIdx.x*256 + threadIdx.x;
  int xx = g & 127, yy = (g>>7)&127, bc = g>>14, c = bc & 255;
  const float* img = x2 + (size_t)bc*HW_;
  const float* w9 = cw + c*9;
  float a = xcs[g];
  #pragma unroll
  for (int dy=-1; dy<=1; dy++){
    int y2 = yy+dy; if ((unsigned)y2 >= 128u) continue;
    #pragma unroll
    for (int dx=-1; dx<=1; dx++){
      int x3 = xx+dx; if ((unsigned)x3 >= 128u) continue;
      a += img[y2*128 + x3] * w9[(dy+1)*3 + (dx+1)];
    }
  }
  xcs[g] = a;
}

// ---- complex channel mix inside low-freq mask: mapped = W @ Xf_low ----
__global__ __launch_bounds__(256) void k_mix(const float2* __restrict__ Xf, const float* __restrict__ wre,
                                             const float* __restrict__ wim, const float* __restrict__ kxp,
                                             const float* __restrict__ kyp, float2* __restrict__ mapped){
  int f = blockIdx.x*256 + threadIdx.x;
  if (f >= F_) return;
  int row = f / WF_, col = f - row*WF_;
  float rowlim = floorf(sigmoidf_(kxp[0])*128.0f);
  float collim = floorf(sigmoidf_(kyp[0])*65.0f);
  if (!((float)row < rowlim && (float)col < collim)) return;
  int b = blockIdx.z, c0 = blockIdx.y*4;
  float ar[4]={0,0,0,0}, ai[4]={0,0,0,0};
  const float2* xb = Xf + (size_t)b*C_*F_ + f;
  for (int d=0; d<C_; d++){
    float2 v = xb[(size_t)d*F_];
    #pragma unroll
    for (int i=0;i<4;i++){
      float wr = wre[(c0+i)*C_ + d];
      float wi = wim[(c0+i)*C_ + d];
      ar[i] += wr*v.x - wi*v.y;
      ai[i] += wr*v.y + wi*v.x;
    }
  }
  #pragma unroll
  for (int i=0;i<4;i++)
    mapped[((size_t)(b*C_ + c0 + i))*F_ + f] = make_float2(ar[i], ai[i]);
}

// ---- inverse col FFT with fused alpha-blend at load; Y1 written in place over mapped ----
__global__ __launch_bounds__(256) void k_inv_cols(const float2* __restrict__ Xf, const float2* __restrict__ mapped,
                                                  const float* __restrict__ alpha, const unsigned char* __restrict__ bid,
                                                  const float* __restrict__ kxp, const float* __restrict__ kyp,
                                                  float2* __restrict__ Y1){
  __shared__ float2 cbuf[13*129];
  __shared__ float2 tw[64];
  __shared__ float al[6];
  int tid = threadIdx.x;
  int chunk = blockIdx.x, slice = blockIdx.y;
  int c0 = chunk*13;
  if (tid < 64){ float s,c; sincosf(6.283185307179586f*(float)tid/128.0f,&s,&c); tw[tid]=make_float2(c,s); }
  if (tid < 6) al[tid] = alpha[slice*6 + tid];
  float rowlim = floorf(sigmoidf_(kxp[0])*128.0f);
  float collim = floorf(sigmoidf_(kyp[0])*65.0f);
  __syncthreads();
  const float2* xfb = Xf + (size_t)slice*F_;
  const float2* mpb = mapped + (size_t)slice*F_;
  for (int p = tid; p < 13*128; p += 256){
    int ky = p / 13, col = p - ky*13, kx = c0 + col;
    int f = ky*WF_ + kx;
    float a = al[(int)bid[f]];
    bool inm = ((float)ky < rowlim) && ((float)kx < collim);
    float2 v;
    if (inm){ v = mpb[f]; v.x *= a; v.y *= a; }
    else    { v = xfb[f]; float om = 1.0f - a; v.x *= om; v.y *= om; }
    cbuf[col*129 + ky] = v;
  }
  fft128_lds<1,13>(cbuf, 129, tid, tw);
  float2* yb = Y1 + (size_t)slice*F_;
  for (int p = tid; p < 13*128; p += 256){
    int y = p / 13, col = p - y*13;
    yb[y*WF_ + c0 + col] = cbuf[col*129 + brev7(y)];
  }
}

// ---- inverse row c2r (pocketfft semantics: Im dropped at kx=0,64), 1/128, + xcs -> sbuf ----
__global__ __launch_bounds__(256) void k_inv_rows(const float2* __restrict__ Y1, const float* __restrict__ xcs,
                                                  float* __restrict__ sbuf){
  __shared__ float2 buf[32*129];
  __shared__ float2 tw[64];
  int tid = threadIdx.x;
  if (tid < 64){ float s,c; sincosf(6.283185307179586f*(float)tid/128.0f,&s,&c); tw[tid]=make_float2(c,s); }
  int slice = blockIdx.x >> 2;
  int r0 = (blockIdx.x & 3) * 32;
  const float2* src = Y1 + (size_t)slice*F_ + (size_t)r0*WF_;
  for (int p = tid; p < 32*WF_; p += 256){
    int row = p / WF_, k = p - row*WF_;
    float2 v = src[p];
    if (k == 0 || k == 64) v.y = 0.0f;
    buf[row*129 + k] = v;
    if (k >= 1 && k <= 63) buf[row*129 + 128 - k] = make_float2(v.x, -v.y);
  }
  fft128_lds<1,32>(buf, 129, tid, tw);
  size_t gbase = (size_t)slice*HW_ + (size_t)r0*128;
  for (int p = tid; p < 32*128; p += 256){
    int row = p >> 7, n = p & 127;
    size_t g = gbase + p;
    sbuf[g] = buf[row*129 + brev7(n)].x * 0.0078125f + xcs[g];
  }
}

// ---- LN stats over channels ----
__global__ __launch_bounds__(256) void k_stats(const float* __restrict__ sbuf, float* __restrict__ stats){
  int g = blockIdx.x*256 + threadIdx.x;
  int b = g >> 14, hw = g & 16383;
  const float* p = sbuf + (size_t)b*C_*HW_ + hw;
  float s1 = 0.0f, s2 = 0.0f;
  for (int c=0; c<C_; c++){
    float v = p[(size_t)c*HW_];
    s1 += v; s2 += v*v;
  }
  float mean = s1 * (1.0f/256.0f);
  float var  = s2 * (1.0f/256.0f) - mean*mean;
  stats[g] = mean;
  stats[65536 + g] = 1.0f / sqrtf(var + 1e-5f);
}

// ---- LN apply + conditional scale/shift, transpose to (B,HW,C) ----
__global__ __launch_bounds__(256) void k_apply(const float* __restrict__ sbuf, const float* __restrict__ stats,
                                               const float* __restrict__ timev,
                                               const float* __restrict__ nww, const float* __restrict__ nwb,
                                               const float* __restrict__ nbw, const float* __restrict__ nbb,
                                               float* __restrict__ out){
  int g = blockIdx.x*256 + threadIdx.x;
  int c = g & 255;
  int hw = (g >> 8) & 16383;
  int b = g >> 22;
  float v = sbuf[((size_t)(b*C_ + c))*HW_ + hw];
  float mean = stats[(b<<14) + hw];
  float rstd = stats[65536 + (b<<14) + hw];
  float t = timev[b];
  float w = t*nww[c] + nwb[c];
  float bi = t*nbw[c] + nbb[c];
  out[g] = w * ((v - mean) * rstd) + bi;
}

extern "C" void kernel_launch(void* const* d_in, const int* in_sizes, int n_in,
                              void* d_out, int out_size, void* d_ws, size_t ws_size,
                              hipStream_t stream){
  const float* x      = (const float*)d_in[0];
  const float* timev  = (const float*)d_in[1];
  const float* w_real = (const float*)d_in[2];
  const float* w_imag = (const float*)d_in[3];
  const float* conv_w = (const float*)d_in[4];
  const float* lin_w  = (const float*)d_in[5];
  const float* lin_b  = (const float*)d_in[6];
  const float* mlp_w1 = (const float*)d_in[7];
  const float* mlp_b1 = (const float*)d_in[8];
  const float* mlp_w2 = (const float*)d_in[9];
  const float* mlp_b2 = (const float*)d_in[10];
  const float* norm_ww= (const float*)d_in[11];
  const float* norm_wb= (const float*)d_in[12];
  const float* norm_bw= (const float*)d_in[13];
  const float* norm_bb= (const float*)d_in[14];
  const float* kxp    = (const float*)d_in[15];
  const float* kyp    = (const float*)d_in[16];

  // workspace layout (floats) — total 50,999,360 floats = 194.6 MiB (same as R2, proven to fit)
  float* ws = (float*)d_ws;
  float*  alpha = ws;                               // 6144
  unsigned char* bid = (unsigned char*)(ws + 6144); // 8320 B (in old bsums region)
  float*  counts= ws + 12288;                       // 8 (padded)
  float*  stats = ws + 12352;                       // 131072 (mean | rstd)
  float*  x2    = ws + 143424;                      // 16,777,216   (x2, later final sum s)
  float2* Xf    = (float2*)(ws + 16920640);         // 8,519,680 f2
  float2* Cb    = (float2*)(ws + 33960000);         // 8,519,680 f2 (X1 -> mapped -> Y1 in place)
  float*  xcs   = (float*)d_out;                    // xc + xl scratch (dead before k_apply)
  float*  out   = (float*)d_out;

  k_transpose    <<<dim3(256, 4, B_), dim3(64,16), 0, stream>>>(x, x2);
  k_counts       <<<1, 256, 0, stream>>>(counts, bid);
  k_fwd_rows     <<<4096, 256, 0, stream>>>(x2, Cb);
  k_fwd_cols_gate<<<1024, 256, 0, stream>>>(Cb, Xf, counts, bid, mlp_w1, mlp_b1, mlp_w2, mlp_b2, alpha);
  k_pointwise    <<<dim3(64, 8, B_), 256, 0, stream>>>(x2, lin_w, lin_b, xcs);
  k_conv         <<<65536, 256, 0, stream>>>(x2, conv_w, xcs);
  k_mix          <<<dim3(33, 64, B_), 256, 0, stream>>>(Xf, w_real, w_imag, kxp, kyp, Cb);
  k_inv_cols     <<<dim3(5, 1024), 256, 0, stream>>>(Xf, Cb, alpha, bid, kxp, kyp, Cb);
  k_inv_rows     <<<4096, 256, 0, stream>>>(Cb, xcs, x2);
  k_stats        <<<256, 256, 0, stream>>>(x2, stats);
  k_apply        <<<65536, 256, 0, stream>>>(x2, stats, timev, norm_ww, norm_wb, norm_bw, norm_bb, out);
}